// Round 9
// baseline (250.414 us; speedup 1.0000x reference)
//
#include <hip/hip_runtime.h>

#define NUM_DEM 2
#define VOCAB 10000
#define EMB 128
#define NROWS 16384
#define ROWLEN (NUM_DEM + VOCAB)      // 10002
#define KSTEPS 313                    // ceil(10000/32)
#define PCOLS 132                     // partial row stride: 128 pooled + 1 count + pad
#define BPACK_USHORTS (KSTEPS * 4096) // 4096 bf16 per K-step tile (32k x 128n)
#define BPACK_BYTES ((size_t)BPACK_USHORTS * 2)
#define NCH 8

typedef float f32x4 __attribute__((ext_vector_type(4)));
typedef float f32x16 __attribute__((ext_vector_type(16)));
typedef __bf16 bf16x8 __attribute__((ext_vector_type(8)));
typedef short s16x8 __attribute__((ext_vector_type(8)));

union Frag {
    s16x8 s;
    bf16x8 b;
    unsigned int u[4];
};

__device__ __forceinline__ unsigned short f2bf_rtne(float f) {
    unsigned int u = __float_as_uint(f);
    u += 0x7FFFu + ((u >> 16) & 1u);
    return (unsigned short)(u >> 16);
}

// ---------------- kernel 0: pack embed (fp32 -> bf16 32x32x16-B fragment order) -----
// Fragment (t, cf, kf): lane l, elem j  <-  embed[t*32 + kf*16 + (l>>5)*8 + j][cf*32 + (l&31)]
// bp[(((t*4 + cf)*2 + kf)*64 + l)*8 + j]
__global__ void pack_embed_k(const float* __restrict__ embed,
                             unsigned short* __restrict__ bp) {
    int id = blockIdx.x * blockDim.x + threadIdx.x;
    if (id >= KSTEPS * 8 * 64) return;
    int l = id & 63;
    int kf = (id >> 6) & 1;
    int cf = (id >> 7) & 3;
    int t = id >> 9;
    int kbase = t * 32 + kf * 16 + ((l >> 5) * 8);
    int n = cf * 32 + (l & 31);
    unsigned short v[8];
#pragma unroll
    for (int j = 0; j < 8; ++j) {
        int k = kbase + j;
        float f = (k < VOCAB) ? embed[(size_t)k * EMB + n] : 0.0f;
        v[j] = f2bf_rtne(f);
    }
    uint4 w;
    w.x = (unsigned int)v[0] | ((unsigned int)v[1] << 16);
    w.y = (unsigned int)v[2] | ((unsigned int)v[3] << 16);
    w.z = (unsigned int)v[4] | ((unsigned int)v[5] << 16);
    w.w = (unsigned int)v[6] | ((unsigned int)v[7] << 16);
    *reinterpret_cast<uint4*>(bp + (size_t)id * 8) = w;
}

// ---------------- kernel 1: split-K masked-sum GEMM via 32x32x16 MFMA ---------------
// Single-pass (A streamed from src), R6 barrier structure (BK=64, double-buffered
// 16 KB LDS, __syncthreads pairs), but 32-row waves + 32x32x16 MFMA: halves LDS
// B-fragment traffic (2.62 -> 1.31 GB) and MFMA/barrier counts per row.
// Row count done with VALU adds on the 0/1 fp32 values (no ones-MFMA).
typedef const __attribute__((address_space(1))) unsigned int* gas_u32p;
typedef __attribute__((address_space(3))) unsigned int* las_u32p;
#define GLOAD_LDS16(g, l)                                                              \
    __builtin_amdgcn_global_load_lds((gas_u32p)(g), (las_u32p)(l), 16, 0, 0)

#define PERM_A(dst, x0, x1)                                                            \
    dst.u[0] = __builtin_amdgcn_perm(__float_as_uint(x0.y), __float_as_uint(x0.x),     \
                                     0x07060302u);                                     \
    dst.u[1] = __builtin_amdgcn_perm(__float_as_uint(x0.w), __float_as_uint(x0.z),     \
                                     0x07060302u);                                     \
    dst.u[2] = __builtin_amdgcn_perm(__float_as_uint(x1.y), __float_as_uint(x1.x),     \
                                     0x07060302u);                                     \
    dst.u[3] = __builtin_amdgcn_perm(__float_as_uint(x1.w), __float_as_uint(x1.z),     \
                                     0x07060302u);

// load 8 fp32 mask values for frag (T_,KF), fold into count, perm to bf16 frag
#define LOAD_A(dst, T_, KF)                                                            \
    {                                                                                  \
        f32x4 x0 = (f32x4){0.f, 0.f, 0.f, 0.f}, x1 = x0;                               \
        int base_ = (T_)*32 + (KF)*16;                                                 \
        if (base_ + klo + 8 <= VOCAB) {                                                \
            const f32x4* ap_ = reinterpret_cast<const f32x4*>(asrc + base_);           \
            x0 = ap_[0];                                                               \
            x1 = ap_[1];                                                               \
        }                                                                              \
        cnt += x0.x + x0.y + x0.z + x0.w + x1.x + x1.y + x1.z + x1.w;                  \
        PERM_A(dst, x0, x1);                                                           \
    }

__global__ __launch_bounds__(256, 4) void main_gemm_k(
    const float* __restrict__ src, const unsigned short* __restrict__ bp,
    float* __restrict__ part, int nch) {
    __shared__ alignas(16) unsigned short ldsB[2 * 4096];  // 16 KB: two K-step B tiles

    const int tid = threadIdx.x;
    const int lane = tid & 63;
    const int wid = tid >> 6;
    const int rb = blockIdx.x & 127;  // row block: 128 rows
    const int ch = blockIdx.x >> 7;   // K chunk
    const int t0 = (KSTEPS * ch) / nch;
    const int t1 = (KSTEPS * (ch + 1)) / nch;

    const int rowbase = rb * 128 + wid * 32;
    const int arow = rowbase + (lane & 31);
    const int klo = (lane >> 5) * 8;
    const float* asrc = src + (size_t)arow * ROWLEN + NUM_DEM + klo;

    f32x16 pacc[4];
#pragma unroll
    for (int cf = 0; cf < 4; ++cf)
#pragma unroll
        for (int r = 0; r < 16; ++r) pacc[cf][r] = 0.f;
    float cnt = 0.f;

    int t = t0;
    for (; t + 2 <= t1; t += 2) {
        // stage B(t) -> buf0, B(t+1) -> buf1 (4 x 16B per thread)
        const unsigned short* gB0 = bp + (size_t)t * 4096 + wid * 1024 + lane * 8;
        const unsigned short* gB1 = gB0 + 4096;
        unsigned short* lB0 = ldsB + wid * 1024 + lane * 8;
        unsigned short* lB1 = lB0 + 4096;
        GLOAD_LDS16(gB0, lB0);
        GLOAD_LDS16(gB0 + 512, lB0 + 512);
        GLOAD_LDS16(gB1, lB1);
        GLOAD_LDS16(gB1 + 512, lB1 + 512);

        // A fragments for steps t, t+1 (fp32 0/1 -> bf16 exact) + VALU row-count
        Frag af[2][2];
        LOAD_A(af[0][0], t, 0);
        LOAD_A(af[0][1], t, 1);
        LOAD_A(af[1][0], t + 1, 0);
        LOAD_A(af[1][1], t + 1, 1);

        __syncthreads();  // both B tiles resident

#pragma unroll
        for (int s = 0; s < 2; ++s) {
#pragma unroll
            for (int cf = 0; cf < 4; ++cf) {
#pragma unroll
                for (int kf = 0; kf < 2; ++kf) {
                    Frag bfr;
                    bfr.s = *reinterpret_cast<const s16x8*>(ldsB + s * 4096 +
                                                            (cf * 2 + kf) * 512 +
                                                            lane * 8);
                    pacc[cf] = __builtin_amdgcn_mfma_f32_32x32x16_bf16(
                        af[s][kf].b, bfr.b, pacc[cf], 0, 0, 0);
                }
            }
        }

        __syncthreads();  // protect LDS before next stage
    }
    if (t < t1) {  // odd tail step
        const unsigned short* gB0 = bp + (size_t)t * 4096 + wid * 1024 + lane * 8;
        unsigned short* lB0 = ldsB + wid * 1024 + lane * 8;
        GLOAD_LDS16(gB0, lB0);
        GLOAD_LDS16(gB0 + 512, lB0 + 512);

        Frag af[2];
        LOAD_A(af[0], t, 0);
        LOAD_A(af[1], t, 1);
        __syncthreads();
#pragma unroll
        for (int cf = 0; cf < 4; ++cf) {
#pragma unroll
            for (int kf = 0; kf < 2; ++kf) {
                Frag bfr;
                bfr.s = *reinterpret_cast<const s16x8*>(ldsB + (cf * 2 + kf) * 512 +
                                                        lane * 8);
                pacc[cf] = __builtin_amdgcn_mfma_f32_32x32x16_bf16(af[kf].b, bfr.b,
                                                                   pacc[cf], 0, 0, 0);
            }
        }
        __syncthreads();
    }

    // epilogue: 32x32 C/D layout col = lane&31, row = (reg&3) + 8*(reg>>2) + 4*(lane>>5)
    const int rlo = 4 * (lane >> 5);
    const int col = lane & 31;
    float* pch = part + (size_t)ch * NROWS * PCOLS;
#pragma unroll
    for (int cf = 0; cf < 4; ++cf) {
#pragma unroll
        for (int r = 0; r < 16; ++r) {
            int row = rowbase + (r & 3) + 8 * (r >> 2) + rlo;
            pch[(size_t)row * PCOLS + cf * 32 + col] = pacc[cf][r];
        }
    }
    float tot = cnt + __shfl_xor(cnt, 32);
    if (lane < 32) pch[(size_t)(rowbase + lane) * PCOLS + 128] = tot;
}

// ---------------- kernel 2: reduce partials + MLP ----------------------------------
__global__ __launch_bounds__(256) void mlp_k(const float* __restrict__ part,
                                             const float* __restrict__ src,
                                             const float* __restrict__ W1,
                                             const float* __restrict__ b1,
                                             const float* __restrict__ W2,
                                             const float* __restrict__ b2,
                                             float* __restrict__ out, int nch) {
    __shared__ float xls[16][131];  // [dem(2), pooled(128)] per row
    __shared__ float hls[16][16];
    __shared__ float cnt[16];
    const int tid = threadIdx.x;
    const int rb = blockIdx.x * 16;

    if (tid < 16) {
        float s = 0.f;
        for (int c = 0; c < nch; ++c)
            s += part[((size_t)c * NROWS + rb + tid) * PCOLS + 128];
        cnt[tid] = s;
    }
    if (tid >= 16 && tid < 48) {
        int r = (tid - 16) >> 1, d = (tid - 16) & 1;
        xls[r][d] = src[(size_t)(rb + r) * ROWLEN + d];
    }
    __syncthreads();

    for (int idx = tid; idx < 16 * 128; idx += 256) {
        int r = idx >> 7, col = idx & 127;
        float s = 0.f;
        for (int c = 0; c < nch; ++c)
            s += part[((size_t)c * NROWS + rb + r) * PCOLS + col];
        xls[r][NUM_DEM + col] = s / cnt[r];
    }
    __syncthreads();

    {
        int r = tid >> 4, u = tid & 15;
        float acc = b1[u];
        for (int i = 0; i < NUM_DEM + EMB; ++i) acc += xls[r][i] * W1[i * 16 + u];
        hls[r][u] = tanhf(acc);
    }
    __syncthreads();

    if (tid < 32) {
        int r = tid >> 1, o = tid & 1;
        float acc = b2[o];
#pragma unroll
        for (int u = 0; u < 16; ++u) acc += hls[r][u] * W2[u * 2 + o];
        out[(size_t)(rb + r) * 2 + o] = acc;
    }
}

// ---------------- launch ------------------------------------------------------------
extern "C" void kernel_launch(void* const* d_in, const int* in_sizes, int n_in,
                              void* d_out, int out_size, void* d_ws, size_t ws_size,
                              hipStream_t stream) {
    const float* src = (const float*)d_in[0];
    const float* embed = (const float*)d_in[1];
    const float* W1 = (const float*)d_in[2];
    const float* b1 = (const float*)d_in[3];
    const float* W2 = (const float*)d_in[4];
    const float* b2 = (const float*)d_in[5];
    float* out = (float*)d_out;

    unsigned short* bpack = (unsigned short*)d_ws;
    float* part = (float*)((char*)d_ws + BPACK_BYTES);

    const size_t part1 = (size_t)NROWS * PCOLS * sizeof(float);
    int nch = NCH;
    while (nch > 1 && BPACK_BYTES + part1 * (size_t)nch > ws_size) nch >>= 1;

    hipLaunchKernelGGL(pack_embed_k, dim3((KSTEPS * 8 * 64 + 255) / 256), dim3(256), 0,
                       stream, embed, bpack);
    hipLaunchKernelGGL(main_gemm_k, dim3(128 * nch), dim3(256), 0, stream, src, bpack,
                       part, nch);
    hipLaunchKernelGGL(mlp_k, dim3(NROWS / 16), dim3(256), 0, stream, part, src, W1, b1,
                       W2, b2, out, nch);
}

// Round 10
// 202.219 us; speedup vs baseline: 1.2383x; 1.2383x over previous
//
#include <hip/hip_runtime.h>

#define NUM_DEM 2
#define VOCAB 10000
#define EMB 128
#define NROWS 16384
#define ROWLEN (NUM_DEM + VOCAB)      // 10002
#define KSTEPS 313                    // ceil(10000/32)
#define TILES (KSTEPS + 1)            // +1 zero pad tile (pipeline may stage step 313)
#define NITER 157                     // BK=64 iterations total
#define PCOLS 132                     // partial row stride: 128 pooled + 1 count + pad
#define BPACK_USHORTS ((size_t)TILES * 4096)
#define BPACK_BYTES (BPACK_USHORTS * 2)
#define NCH 4

typedef float f32x4 __attribute__((ext_vector_type(4)));
typedef __bf16 bf16x8 __attribute__((ext_vector_type(8)));
typedef short s16x8 __attribute__((ext_vector_type(8)));

union Frag {
    s16x8 s;
    bf16x8 b;
    unsigned int u[4];
};

__device__ __forceinline__ unsigned short f2bf_rtne(float f) {
    unsigned int u = __float_as_uint(f);
    u += 0x7FFFu + ((u >> 16) & 1u);
    return (unsigned short)(u >> 16);
}

// ---------------- kernel 0: pack embed (fp32 -> bf16 MFMA-B fragment order) ---------
// Bpack[((t*8 + c)*64 + l)*8 + j] = bf16(embed[t*32 + (l>>4)*8 + j][c*16 + (l&15)])
// t == 313 is an all-zero pad tile (kbase >= VOCAB).
__global__ void pack_embed_k(const float* __restrict__ embed,
                             unsigned short* __restrict__ bp) {
    int id = blockIdx.x * blockDim.x + threadIdx.x;
    if (id >= TILES * 8 * 64) return;
    int l = id & 63;
    int c = (id >> 6) & 7;
    int t = id >> 9;
    int kbase = t * 32 + ((l >> 4) * 8);
    int n = c * 16 + (l & 15);
    unsigned short v[8];
#pragma unroll
    for (int j = 0; j < 8; ++j) {
        int k = kbase + j;
        float f = (k < VOCAB) ? embed[(size_t)k * EMB + n] : 0.0f;
        v[j] = f2bf_rtne(f);
    }
    uint4 w;
    w.x = (unsigned int)v[0] | ((unsigned int)v[1] << 16);
    w.y = (unsigned int)v[2] | ((unsigned int)v[3] << 16);
    w.z = (unsigned int)v[4] | ((unsigned int)v[5] << 16);
    w.w = (unsigned int)v[6] | ((unsigned int)v[7] << 16);
    *reinterpret_cast<uint4*>(bp + (size_t)id * 8) = w;
}

// ---------------- kernel 1: split-K masked-sum GEMM, counted-vmcnt pipeline ---------
// R6 geometry (16x16x32, 64-row blocks, BK=64, nch=4, occupancy 4). Double-buffered
// 32 KB LDS, prefetch distance 1 iter for B (global_load_lds) and A (regs).
// Steady state per iter: s_waitcnt vmcnt(8); s_barrier; compute; s_barrier; issue 8.
// No vmcnt(0) drain -> HBM A-latency hidden behind one iter of compute.
typedef const __attribute__((address_space(1))) unsigned int* gas_u32p;
typedef __attribute__((address_space(3))) unsigned int* las_u32p;
#define GLOAD_LDS16(g, l)                                                              \
    __builtin_amdgcn_global_load_lds((gas_u32p)(g), (las_u32p)(l), 16, 0, 0)

#define PERM_A(dst, x0, x1)                                                            \
    dst.u[0] = __builtin_amdgcn_perm(__float_as_uint(x0.y), __float_as_uint(x0.x),     \
                                     0x07060302u);                                     \
    dst.u[1] = __builtin_amdgcn_perm(__float_as_uint(x0.w), __float_as_uint(x0.z),     \
                                     0x07060302u);                                     \
    dst.u[2] = __builtin_amdgcn_perm(__float_as_uint(x1.y), __float_as_uint(x1.x),     \
                                     0x07060302u);                                     \
    dst.u[3] = __builtin_amdgcn_perm(__float_as_uint(x1.w), __float_as_uint(x1.z),     \
                                     0x07060302u);

#define WAITVM(N) asm volatile("s_waitcnt vmcnt(" #N ")" ::: "memory")

// stage iter G's two 32-k tiles (2*G, 2*G+1) into LDS buffer BUF: 4 x 16B per thread
#define STAGE_B(G, BUF)                                                                \
    {                                                                                  \
        const unsigned short* gB_ =                                                    \
            bp + (size_t)(2 * (G)) * 4096 + wid * 1024 + lane * 8;                     \
        unsigned short* lB_ = &ldsB[BUF][0] + wid * 1024 + lane * 8;                   \
        GLOAD_LDS16(gB_, lB_);                                                         \
        GLOAD_LDS16(gB_ + 512, lB_ + 512);                                             \
        GLOAD_LDS16(gB_ + 4096, lB_ + 4096);                                           \
        GLOAD_LDS16(gB_ + 4096 + 512, lB_ + 4096 + 512);                               \
    }

// unconditional clamped A loads for iter G (4 vmem): OOB groups zeroed at consume
#define LOAD_A2(G, A0, A1, A2, A3)                                                     \
    {                                                                                  \
        const int s0_ = 2 * (G), s1_ = s0_ + 1;                                        \
        const f32x4* p0_ = reinterpret_cast<const f32x4*>(                             \
            asrc + ((s0_ * 32 + kgrp8 + 8 <= VOCAB) ? (size_t)(s0_ * 32) : (size_t)0));\
        const f32x4* p1_ = reinterpret_cast<const f32x4*>(                             \
            asrc + ((s1_ * 32 + kgrp8 + 8 <= VOCAB) ? (size_t)(s1_ * 32) : (size_t)0));\
        A0 = p0_[0];                                                                   \
        A1 = p0_[1];                                                                   \
        A2 = p1_[0];                                                                   \
        A3 = p1_[1];                                                                   \
    }

#define BODY(G, BUF, A0, A1, A2, A3, DOPF, PFG, N)                                     \
    {                                                                                  \
        WAITVM(N);                                                                     \
        __builtin_amdgcn_s_barrier();                                                  \
        asm volatile("" ::: "memory"); /* pin ds_reads below the barrier */            \
        {                                                                              \
            const int s0_ = 2 * (G), s1_ = s0_ + 1;                                    \
            Frag af0_, af1_;                                                           \
            PERM_A(af0_, A0, A1); /* fp32 0/1 -> bf16 truncation exact */              \
            PERM_A(af1_, A2, A3);                                                      \
            unsigned v0_ = (s0_ * 32 + kgrp8 + 8 <= VOCAB) ? 0xFFFFFFFFu : 0u;         \
            unsigned v1_ = (s1_ * 32 + kgrp8 + 8 <= VOCAB) ? 0xFFFFFFFFu : 0u;         \
            af0_.u[0] &= v0_; af0_.u[1] &= v0_; af0_.u[2] &= v0_; af0_.u[3] &= v0_;    \
            af1_.u[0] &= v1_; af1_.u[1] &= v1_; af1_.u[2] &= v1_; af1_.u[3] &= v1_;    \
            const unsigned short* rB_ = &ldsB[BUF][0] + lane * 8;                      \
            _Pragma("unroll") for (int f = 0; f < 8; ++f) {                            \
                Frag bfr_;                                                             \
                bfr_.s = *reinterpret_cast<const s16x8*>(rB_ + f * 512);               \
                pacc[f] = __builtin_amdgcn_mfma_f32_16x16x32_bf16(af0_.b, bfr_.b,      \
                                                                  pacc[f], 0, 0, 0);   \
            }                                                                          \
            cacc = __builtin_amdgcn_mfma_f32_16x16x32_bf16(af0_.b, onesf.b, cacc, 0,   \
                                                           0, 0);                      \
            _Pragma("unroll") for (int f = 0; f < 8; ++f) {                            \
                Frag bfr_;                                                             \
                bfr_.s = *reinterpret_cast<const s16x8*>(rB_ + 4096 + f * 512);        \
                pacc[f] = __builtin_amdgcn_mfma_f32_16x16x32_bf16(af1_.b, bfr_.b,      \
                                                                  pacc[f], 0, 0, 0);   \
            }                                                                          \
            cacc = __builtin_amdgcn_mfma_f32_16x16x32_bf16(af1_.b, onesf.b, cacc, 0,   \
                                                           0, 0);                      \
        }                                                                              \
        asm volatile("" ::: "memory"); /* pin ds_reads above this barrier */           \
        __builtin_amdgcn_s_barrier();                                                  \
        __builtin_amdgcn_sched_barrier(0);                                             \
        if (DOPF) {                                                                    \
            STAGE_B(PFG, BUF);                                                         \
            LOAD_A2(PFG, A0, A1, A2, A3);                                              \
        }                                                                              \
    }

__global__ __launch_bounds__(256, 4) void main_gemm_k(
    const float* __restrict__ src, const unsigned short* __restrict__ bp,
    float* __restrict__ part, int nch) {
    __shared__ alignas(16) unsigned short ldsB[2][2 * 4096];  // 32 KB double buffer

    const int tid = threadIdx.x;
    const int lane = tid & 63;
    const int wid = tid >> 6;
    const int rb = blockIdx.x & 255;  // row block: 64 rows
    const int ch = blockIdx.x >> 8;   // K chunk (iter-granular split)
    const int I0 = (NITER * ch) / nch;
    const int I1 = (NITER * (ch + 1)) / nch;
    const int nIter = I1 - I0;  // 39 or 40

    const int rowbase = rb * 64 + wid * 16;
    const int arow = rowbase + (lane & 15);
    const int kgrp8 = (lane >> 4) * 8;
    const float* asrc = src + (size_t)arow * ROWLEN + NUM_DEM + kgrp8;

    f32x4 pacc[8];
#pragma unroll
    for (int f = 0; f < 8; ++f) pacc[f] = (f32x4){0.f, 0.f, 0.f, 0.f};
    f32x4 cacc = (f32x4){0.f, 0.f, 0.f, 0.f};

    Frag onesf;  // B fragment with col 0 == 1.0 (row counts), others 0
    {
        unsigned short o = ((lane & 15) == 0) ? (unsigned short)0x3F80 : (unsigned short)0;
        unsigned int ow = (unsigned int)o | ((unsigned int)o << 16);
        onesf.u[0] = ow; onesf.u[1] = ow; onesf.u[2] = ow; onesf.u[3] = ow;
    }

    f32x4 aP0, aP1, aP2, aP3, aQ0, aQ1, aQ2, aQ3;  // A slots, parity-named (rule #20)

    // prologue: iters I0 -> buf0/P, I0+1 -> buf1/Q (groups fenced for vmcnt order)
    STAGE_B(I0, 0);
    LOAD_A2(I0, aP0, aP1, aP2, aP3);
    asm volatile("" ::: "memory");
    STAGE_B(I0 + 1, 1);
    LOAD_A2(I0 + 1, aQ0, aQ1, aQ2, aQ3);
    // outstanding: B(0),A(0),B(1),A(1) = 16 vmem

    int i = 0;
    for (; i + 3 < nIter; i += 2) {
        BODY(I0 + i, 0, aP0, aP1, aP2, aP3, 1, I0 + i + 2, 8);
        BODY(I0 + i + 1, 1, aQ0, aQ1, aQ2, aQ3, 1, I0 + i + 3, 8);
    }
    if (nIter - i == 3) {
        BODY(I0 + i, 0, aP0, aP1, aP2, aP3, 1, I0 + i + 2, 8);
        BODY(I0 + i + 1, 1, aQ0, aQ1, aQ2, aQ3, 0, 0, 8);
        BODY(I0 + i + 2, 0, aP0, aP1, aP2, aP3, 0, 0, 0);
    } else {  // nIter - i == 2
        BODY(I0 + i, 0, aP0, aP1, aP2, aP3, 0, 0, 8);
        BODY(I0 + i + 1, 1, aQ0, aQ1, aQ2, aQ3, 0, 0, 0);
    }

    // epilogue: C/D layout col = lane&15, row = (lane>>4)*4 + reg
    const int rlo = (lane >> 4) * 4;
    float* pch = part + (size_t)ch * NROWS * PCOLS;
#pragma unroll
    for (int f = 0; f < 8; ++f) {
#pragma unroll
        for (int r = 0; r < 4; ++r) {
            int row = rowbase + rlo + r;
            pch[(size_t)row * PCOLS + f * 16 + (lane & 15)] = pacc[f][r];
        }
    }
    if ((lane & 15) == 0) {
#pragma unroll
        for (int r = 0; r < 4; ++r) {
            int row = rowbase + rlo + r;
            pch[(size_t)row * PCOLS + 128] = cacc[r];
        }
    }
}

// ---------------- kernel 2: reduce partials + MLP ----------------------------------
__global__ __launch_bounds__(256) void mlp_k(const float* __restrict__ part,
                                             const float* __restrict__ src,
                                             const float* __restrict__ W1,
                                             const float* __restrict__ b1,
                                             const float* __restrict__ W2,
                                             const float* __restrict__ b2,
                                             float* __restrict__ out, int nch) {
    __shared__ float xls[16][131];  // [dem(2), pooled(128)] per row
    __shared__ float hls[16][16];
    __shared__ float cnt[16];
    const int tid = threadIdx.x;
    const int rb = blockIdx.x * 16;

    if (tid < 16) {
        float s = 0.f;
        for (int c = 0; c < nch; ++c)
            s += part[((size_t)c * NROWS + rb + tid) * PCOLS + 128];
        cnt[tid] = s;
    }
    if (tid >= 16 && tid < 48) {
        int r = (tid - 16) >> 1, d = (tid - 16) & 1;
        xls[r][d] = src[(size_t)(rb + r) * ROWLEN + d];
    }
    __syncthreads();

    for (int idx = tid; idx < 16 * 128; idx += 256) {
        int r = idx >> 7, col = idx & 127;
        float s = 0.f;
        for (int c = 0; c < nch; ++c)
            s += part[((size_t)c * NROWS + rb + r) * PCOLS + col];
        xls[r][NUM_DEM + col] = s / cnt[r];
    }
    __syncthreads();

    {
        int r = tid >> 4, u = tid & 15;
        float acc = b1[u];
        for (int i = 0; i < NUM_DEM + EMB; ++i) acc += xls[r][i] * W1[i * 16 + u];
        hls[r][u] = tanhf(acc);
    }
    __syncthreads();

    if (tid < 32) {
        int r = tid >> 1, o = tid & 1;
        float acc = b2[o];
#pragma unroll
        for (int u = 0; u < 16; ++u) acc += hls[r][u] * W2[u * 2 + o];
        out[(size_t)(rb + r) * 2 + o] = acc;
    }
}

// ---------------- launch ------------------------------------------------------------
extern "C" void kernel_launch(void* const* d_in, const int* in_sizes, int n_in,
                              void* d_out, int out_size, void* d_ws, size_t ws_size,
                              hipStream_t stream) {
    const float* src = (const float*)d_in[0];
    const float* embed = (const float*)d_in[1];
    const float* W1 = (const float*)d_in[2];
    const float* b1 = (const float*)d_in[3];
    const float* W2 = (const float*)d_in[4];
    const float* b2 = (const float*)d_in[5];
    float* out = (float*)d_out;

    unsigned short* bpack = (unsigned short*)d_ws;
    float* part = (float*)((char*)d_ws + BPACK_BYTES);

    const size_t part1 = (size_t)NROWS * PCOLS * sizeof(float);
    int nch = NCH;
    while (nch > 1 && BPACK_BYTES + part1 * (size_t)nch > ws_size) nch >>= 1;

    hipLaunchKernelGGL(pack_embed_k, dim3((TILES * 8 * 64 + 255) / 256), dim3(256), 0,
                       stream, embed, bpack);
    hipLaunchKernelGGL(main_gemm_k, dim3(256 * nch), dim3(256), 0, stream, src, bpack,
                       part, nch);
    hipLaunchKernelGGL(mlp_k, dim3(NROWS / 16), dim3(256), 0, stream, part, src, W1, b1,
                       W2, b2, out, nch);
}